// Round 10
// baseline (312.189 us; speedup 1.0000x reference)
//
#include <hip/hip_runtime.h>
#include <math.h>

#define NN 100000
#define EE 1600000
#define GG 512
#define INF_ 128
#define HID 64
#define EPS 1e-5f

#define NBUK 391          // ceil(NN/256), bucket = dst >> 8
#define P1_TILES 98       // ceil((EE/4)/4096)
#define SETUP_B 25        // covers setup span (6240 < 25*256)
#define POOL_WORDS (GG * 64 * 2 + GG)
#define ZERO_B ((POOL_WORDS + 255) / 256)

typedef unsigned int uint32;
typedef __attribute__((ext_vector_type(8))) short bf16x8;
typedef __attribute__((ext_vector_type(4))) float f32x4;

// bf16 helpers: RNE pack, shift decode
static __device__ inline uint32 f2bf(float f) {
    uint32 u = __float_as_uint(f);
    return (u + 0x7FFFu + ((u >> 16) & 1u)) >> 16;
}
static __device__ inline float bf_lo(uint32 u) { return __uint_as_float(u << 16); }
static __device__ inline float bf_hi(uint32 u) { return __uint_as_float(u & 0xFFFF0000u); }

// R10: edge weight folded into features (hw' = hw*dinv[row], agg = di*Σhw'[src]);
// gather needs no per-edge weight -> no random dinv gather, half the shfls.
// Invalid tail slots read zeroed row NN of hwb.

// ---------------- CSR build: 2-level counting sort, single-histogram ------
// R3: per-edge atomic scatter -> 12x cross-XCD write amplification; bucketed.
// R7: chunk-split gather quadruplicated per-edge overhead -> reverted.
// R9: hist once -> hblk; scan2 derives run bases; p1b only scatters.
// R10: hblk/rbase bucket-major so scan2's serial loop streams contiguously.

// blocks [0,98): per-block dst histogram. [98,123): setup. rest: zero pool.
__global__ __launch_bounds__(256) void k_hist1(const int* __restrict__ ei,
        int* __restrict__ hblk,
        const float* b1, const float* g1, const float* be1,
        const float* rm1, const float* rv1,
        const float* b2, const float* g2, const float* be2,
        const float* rm2, const float* rv2, float* sc,
        const float* W1, uint32* Wt1b, const float* W2, uint32* Wt2b,
        uint32* hwb, float* poolz) {
    int b = blockIdx.x, t = threadIdx.x;
    if (b < P1_TILES) {
        __shared__ int h[NBUK];
        for (int i = t; i < NBUK; i += 256) h[i] = 0;
        __syncthreads();
        const int4* dst4 = (const int4*)(ei + EE);
        int base4 = b * 4096;
        for (int j = 0; j < 16; ++j) {
            int i4 = base4 + j * 256 + t;
            if (i4 < EE / 4) {
                int4 d = dst4[i4];
                atomicAdd(&h[d.x >> 8], 1);
                atomicAdd(&h[d.y >> 8], 1);
                atomicAdd(&h[d.z >> 8], 1);
                atomicAdd(&h[d.w >> 8], 1);
            }
        }
        __syncthreads();
        for (int i = t; i < NBUK; i += 256) hblk[i * P1_TILES + b] = h[i];
    } else if (b < P1_TILES + SETUP_B) {
        int i = (b - P1_TILES) * 256 + t;
        if (i < 4096) {                       // Wt1b: K=128
            int n = i >> 6, kp = (i & 63) * 2;
            Wt1b[i] = f2bf(W1[(size_t)kp * 64 + n]) |
                      (f2bf(W1[(size_t)(kp + 1) * 64 + n]) << 16);
        } else if (i < 6144) {                // Wt2b: K=64
            int j = i - 4096;
            int n = j >> 5, kp = (j & 31) * 2;
            Wt2b[j] = f2bf(W2[(size_t)kp * 64 + n]) |
                      (f2bf(W2[(size_t)(kp + 1) * 64 + n]) << 16);
        } else if (i < 6208) {                // BN fold
            int l = i - 6144;
            float s1 = g1[l] * rsqrtf(rv1[l] + EPS);
            sc[l]       = s1;
            sc[64 + l]  = (b1[l] - rm1[l]) * s1 + be1[l];
            float s2 = g2[l] * rsqrtf(rv2[l] + EPS);
            sc[128 + l] = s2;
            sc[192 + l] = (b2[l] - rm2[l]) * s2 + be2[l];
        } else if (i < 6240) {                // zero row NN of hwb
            hwb[(size_t)NN * 32 + (i - 6208)] = 0u;
        }
    } else {
        int i = (b - P1_TILES - SETUP_B) * 256 + t;
        if (i < POOL_WORDS) poolz[i] = 0.f;
    }
}

// one block, 512 threads: bucket totals + scan -> bbase; per-block run bases.
__global__ void k_scan2(const int* __restrict__ hblk, int* __restrict__ bbase,
                        int* __restrict__ rbase, int* __restrict__ offs) {
    __shared__ int wsum[8];
    int t = threadIdx.x;  // 512
    int lane = t & 63, w = t >> 6;
    int c = 0;
    if (t < NBUK)
        for (int b = 0; b < P1_TILES; ++b) c += hblk[t * P1_TILES + b];
    int v = c;
    for (int d = 1; d < 64; d <<= 1) { int n = __shfl_up(v, d); if (lane >= d) v += n; }
    if (lane == 63) wsum[w] = v;
    __syncthreads();
    int pre = 0;
    for (int q = 0; q < w; ++q) pre += wsum[q];
    int excl = pre + v - c;
    if (t <= NBUK) bbase[t] = excl;
    if (t == 0) offs[NN] = EE;
    if (t < NBUK) {
        int run = excl;
        for (int b = 0; b < P1_TILES; ++b) {
            rbase[t * P1_TILES + b] = run;
            run += hblk[t * P1_TILES + b];
        }
    }
}

// scatter packed (src<<8)|(dst&255) into CSR-ordered bucket regions
__global__ __launch_bounds__(256) void k_p1b(const int* __restrict__ ei,
                                             const int* __restrict__ rbase,
                                             uint32* __restrict__ pairs) {
    __shared__ int h[NBUK];
    int b = blockIdx.x, t = threadIdx.x;
    for (int i = t; i < NBUK; i += 256) h[i] = rbase[i * P1_TILES + b];
    __syncthreads();
    const int4* src4 = (const int4*)ei;
    const int4* dst4 = (const int4*)(ei + EE);
    int base4 = b * 4096;
    for (int j = 0; j < 16; ++j) {
        int i4 = base4 + j * 256 + t;
        if (i4 < EE / 4) {
            int4 d = dst4[i4];
            int4 s = src4[i4];
            int p0 = atomicAdd(&h[d.x >> 8], 1);
            pairs[p0] = ((uint32)s.x << 8) | (uint32)(d.x & 255);
            int p1 = atomicAdd(&h[d.y >> 8], 1);
            pairs[p1] = ((uint32)s.y << 8) | (uint32)(d.y & 255);
            int p2 = atomicAdd(&h[d.z >> 8], 1);
            pairs[p2] = ((uint32)s.z << 8) | (uint32)(d.z & 255);
            int p3 = atomicAdd(&h[d.w >> 8], 1);
            pairs[p3] = ((uint32)s.w << 8) | (uint32)(d.w & 255);
        }
    }
}

// per-bucket (256 nodes) CSR finalize in LDS: count, scan, scatter col
__global__ __launch_bounds__(256) void k_p2(const uint32* __restrict__ pairs,
                                            const int* __restrict__ bbase,
                                            int* __restrict__ offs, float* __restrict__ dinv,
                                            int* __restrict__ col) {
    int b = blockIdx.x, t = threadIdx.x;
    int nbase = b << 8;
    int ebase = bbase[b], eend = bbase[b + 1];
    int m = eend - ebase;
    __shared__ int cnt[256];
    __shared__ int wsum[4];
    cnt[t] = 0;
    __syncthreads();
    for (int i = t; i < m; i += 256)
        atomicAdd(&cnt[pairs[ebase + i] & 255u], 1);
    __syncthreads();
    int c = cnt[t];
    int lane = t & 63, w = t >> 6;
    int v = c;
    for (int d = 1; d < 64; d <<= 1) { int n = __shfl_up(v, d); if (lane >= d) v += n; }
    if (lane == 63) wsum[w] = v;
    __syncthreads();
    int pre = 0;
    for (int q = 0; q < w; ++q) pre += wsum[q];
    int excl = pre + v - c;
    int node = nbase + t;
    if (node < NN) {
        offs[node] = ebase + excl;
        dinv[node] = rsqrtf(1.f + (float)c);
    }
    __syncthreads();
    cnt[t] = excl;
    __syncthreads();
    for (int i = t; i < m; i += 256) {
        uint32 u = pairs[ebase + i];
        int loc = atomicAdd(&cnt[u & 255u], 1);
        col[ebase + loc] = (int)(u >> 8);
    }
}

// ---------------- MFMA GEMM: [nrows,K]f32 @ [K,64]bf16 -> bf16' packed ----
// Output rows pre-scaled by dinv[row] (weight folding). 64x64 tile/block,
// 16x16x32 bf16 MFMA. Rows padded +8 bf16: frag loads 2-way conflict (free).
template <int K>
__global__ __launch_bounds__(256) void k_gemm_mfma(const float* __restrict__ X,
                                                   const uint32* __restrict__ Wtb,
                                                   const float* __restrict__ dinv,
                                                   uint32* __restrict__ outb, int nrows) {
    constexpr int KP = K + 8;
    __shared__ alignas(16) unsigned short Al[64 * KP];
    __shared__ alignas(16) unsigned short Bl[64 * KP];
    int tid = threadIdx.x;
    for (int i = tid; i < 64 * (K / 2); i += 256) {
        int n = i / (K / 2), kp = i % (K / 2);
        *(uint32*)&Bl[n * KP + kp * 2] = Wtb[i];
    }
    int r0 = blockIdx.x * 64;
    const float* Xb = X + (size_t)r0 * K;
    int limit = (nrows - r0) * K;
    for (int f = tid * 4; f < 64 * K; f += 1024) {
        float4 v = {0.f, 0.f, 0.f, 0.f};
        if (f + 3 < limit) v = *(const float4*)&Xb[f];
        int row = f / K, kpos = f % K;
        ushort4 pk;
        pk.x = (unsigned short)f2bf(v.x);
        pk.y = (unsigned short)f2bf(v.y);
        pk.z = (unsigned short)f2bf(v.z);
        pk.w = (unsigned short)f2bf(v.w);
        *(ushort4*)&Al[row * KP + kpos] = pk;
    }
    __syncthreads();
    int lane = tid & 63, wv = tid >> 6;
    int m = lane & 15, quad = lane >> 4;
    f32x4 acc0 = {0.f, 0.f, 0.f, 0.f}, acc1 = acc0, acc2 = acc0, acc3 = acc0;
    int arow = wv * 16 + m;
#pragma unroll
    for (int k0 = 0; k0 < K; k0 += 32) {
        int koff = k0 + quad * 8;
        bf16x8 a = *(const bf16x8*)&Al[arow * KP + koff];
        bf16x8 b0 = *(const bf16x8*)&Bl[(0 * 16 + m) * KP + koff];
        bf16x8 b1 = *(const bf16x8*)&Bl[(1 * 16 + m) * KP + koff];
        bf16x8 b2 = *(const bf16x8*)&Bl[(2 * 16 + m) * KP + koff];
        bf16x8 b3 = *(const bf16x8*)&Bl[(3 * 16 + m) * KP + koff];
        acc0 = __builtin_amdgcn_mfma_f32_16x16x32_bf16(a, b0, acc0, 0, 0, 0);
        acc1 = __builtin_amdgcn_mfma_f32_16x16x32_bf16(a, b1, acc1, 0, 0, 0);
        acc2 = __builtin_amdgcn_mfma_f32_16x16x32_bf16(a, b2, acc2, 0, 0, 0);
        acc3 = __builtin_amdgcn_mfma_f32_16x16x32_bf16(a, b3, acc3, 0, 0, 0);
    }
    // C/D layout: col = nt*16 + m, row = quad*4 + reg.
    float dsc[4];
#pragma unroll
    for (int reg = 0; reg < 4; ++reg) {
        int row = r0 + wv * 16 + quad * 4 + reg;
        dsc[reg] = (row < nrows) ? dinv[row] : 0.f;
    }
    const float* accs[4] = {(const float*)&acc0, (const float*)&acc1,
                            (const float*)&acc2, (const float*)&acc3};
#pragma unroll
    for (int nt = 0; nt < 4; ++nt) {
#pragma unroll
        for (int reg = 0; reg < 4; ++reg) {
            float val = accs[nt][reg] * dsc[reg];
            float nxt = __shfl_down(val, 1);
            int row = r0 + wv * 16 + quad * 4 + reg;
            if (((m & 1) == 0) && row < nrows)
                outb[(size_t)row * 32 + nt * 8 + (m >> 1)] =
                    f2bf(val) | (f2bf(nxt) << 16);
        }
    }
}

// ---- fused GCN aggregate + selfloop + BN + ReLU (+resid), weight-folded ---
// One wave per node; 16 lanes x uint2 (4 features) per row, 4 quarters =
// 4 edges per load step, 16 edges per j-iter: 4 shfl + 4 loads + 16 adds.
// Tail slots point at zeroed row NN.
__global__ void k_gcn_gather(const uint32* __restrict__ hwb, const int* __restrict__ col,
                             const int* __restrict__ offs,
                             const float* __restrict__ dinv, const float* __restrict__ scale,
                             const float* __restrict__ shift, const float* __restrict__ resid,
                             float* __restrict__ out) {
    int node = blockIdx.x * 4 + (threadIdx.x >> 6);
    if (node >= NN) return;
    int lane = threadIdx.x & 63;
    int q = lane >> 4;
    int fl = lane & 15;                 // uint2 pos: features {4fl..4fl+3}
    const uint2* hw2 = (const uint2*)hwb;
    int e0 = offs[node], e1 = offs[node + 1];
    float di = dinv[node];
    float a0 = 0.f, a1 = 0.f, a2 = 0.f, a3 = 0.f;
    float c0 = 0.f, c1 = 0.f, c2 = 0.f, c3 = 0.f;
    for (int base = e0; base < e1; base += 64) {
        int m = e1 - base; if (m > 64) m = 64;
        int srcv = NN;                  // zero row for tail slots
        if (lane < m) srcv = col[base + lane];
        for (int j = 0; j < m; j += 16) {
            int sa = __shfl(srcv, j + q);
            int sb = __shfl(srcv, j + 4 + q);
            int sc = __shfl(srcv, j + 8 + q);
            int sd = __shfl(srcv, j + 12 + q);
            uint2 ua = hw2[(size_t)sa * 16 + fl];
            uint2 ub = hw2[(size_t)sb * 16 + fl];
            uint2 uc = hw2[(size_t)sc * 16 + fl];
            uint2 ud = hw2[(size_t)sd * 16 + fl];
            a0 += bf_lo(ua.x); a1 += bf_hi(ua.x); a2 += bf_lo(ua.y); a3 += bf_hi(ua.y);
            c0 += bf_lo(ub.x); c1 += bf_hi(ub.x); c2 += bf_lo(ub.y); c3 += bf_hi(ub.y);
            a0 += bf_lo(uc.x); a1 += bf_hi(uc.x); a2 += bf_lo(uc.y); a3 += bf_hi(uc.y);
            c0 += bf_lo(ud.x); c1 += bf_hi(ud.x); c2 += bf_lo(ud.y); c3 += bf_hi(ud.y);
        }
    }
    a0 += c0; a1 += c1; a2 += c2; a3 += c3;
    a0 += __shfl_xor(a0, 16); a1 += __shfl_xor(a1, 16);
    a2 += __shfl_xor(a2, 16); a3 += __shfl_xor(a3, 16);
    a0 += __shfl_xor(a0, 32); a1 += __shfl_xor(a1, 32);
    a2 += __shfl_xor(a2, 32); a3 += __shfl_xor(a3, 32);
    if (q == 0) {
        uint2 us = hw2[(size_t)node * 16 + fl];   // self term: hw'[node]
        a0 += bf_lo(us.x); a1 += bf_hi(us.x);
        a2 += bf_lo(us.y); a3 += bf_hi(us.y);
        float4 sc4 = *(const float4*)&scale[4 * fl];
        float4 sh4 = *(const float4*)&shift[4 * fl];
        float v0 = fmaxf(fmaf(a0 * di, sc4.x, sh4.x), 0.f);
        float v1 = fmaxf(fmaf(a1 * di, sc4.y, sh4.y), 0.f);
        float v2 = fmaxf(fmaf(a2 * di, sc4.z, sh4.z), 0.f);
        float v3 = fmaxf(fmaf(a3 * di, sc4.w, sh4.w), 0.f);
        size_t oidx = (size_t)node * 64 + 4 * fl;
        if (resid) {
            float4 rv = *(const float4*)&resid[oidx];
            v0 += rv.x; v1 += rv.y; v2 += rv.z; v3 += rv.w;
        }
        float4 o; o.x = v0; o.y = v1; o.z = v2; o.w = v3;
        *(float4*)&out[oidx] = o;
    }
}

// ---------------- pooling over sorted batch, 4 waves x 32 nodes -----------
__global__ __launch_bounds__(256) void k_pool(const float* __restrict__ h,
                       const int* __restrict__ batch,
                       float* __restrict__ msum, float* __restrict__ mmax,
                       float* __restrict__ gcnt) {
    int lane = threadIdx.x & 63;
    int wv = threadIdx.x >> 6;
    int i0 = blockIdx.x * 128 + wv * 32;
    if (i0 >= NN) return;
    int i1 = i0 + 32; if (i1 > NN) i1 = NN;
    int cur = batch[i0];
    float sum = 0.f, mx = 0.f; int c = 0;
    for (int i = i0; i < i1; ++i) {
        int g = batch[i];
        if (g != cur) {
            atomicAdd(&msum[cur * 64 + lane], sum);
            atomicMax((unsigned int*)&mmax[cur * 64 + lane], __float_as_uint(mx));
            if (lane == 0) atomicAdd(&gcnt[cur], (float)c);
            sum = 0.f; mx = 0.f; c = 0; cur = g;
        }
        float v = h[(long)i * 64 + lane];
        sum += v; mx = fmaxf(mx, v); ++c;
    }
    atomicAdd(&msum[cur * 64 + lane], sum);
    atomicMax((unsigned int*)&mmax[cur * 64 + lane], __float_as_uint(mx));
    if (lane == 0) atomicAdd(&gcnt[cur], (float)c);
}

// ---------------- MLP head, one block per graph ----------------
__global__ void k_head(const float* __restrict__ msum, const float* __restrict__ mmax,
                       const float* __restrict__ gcnt,
                       const float* __restrict__ Wh1, const float* __restrict__ bh1,
                       const float* __restrict__ Wh2, const float* __restrict__ bh2,
                       const float* __restrict__ Wh3, const float* __restrict__ bh3,
                       float* __restrict__ out) {
    int g = blockIdx.x, t = threadIdx.x;  // 64 threads
    __shared__ float hg[128];
    __shared__ float z1[64];
    __shared__ float z2[32];
    float c = fmaxf(gcnt[g], 1.f);
    hg[t]      = msum[g * 64 + t] / c;
    hg[64 + t] = mmax[g * 64 + t];
    __syncthreads();
    float acc = bh1[t];
#pragma unroll 8
    for (int k = 0; k < 128; ++k) acc = fmaf(hg[k], Wh1[k * 64 + t], acc);
    z1[t] = fmaxf(acc, 0.f);
    __syncthreads();
    if (t < 32) {
        float a2 = bh2[t];
#pragma unroll 8
        for (int k = 0; k < 64; ++k) a2 = fmaf(z1[k], Wh2[k * 32 + t], a2);
        z2[t] = fmaxf(a2, 0.f);
    }
    __syncthreads();
    if (t == 0) {
        float a3 = bh3[0];
        for (int k = 0; k < 32; ++k) a3 = fmaf(z2[k], Wh3[k], a3);
        out[g] = 1.f / (1.f + expf(-a3));
    }
}

// ---------------- launcher ----------------

static inline size_t alignup(size_t x) { return (x + 255) & ~(size_t)255; }

extern "C" void kernel_launch(void* const* d_in, const int* in_sizes, int n_in,
                              void* d_out, int out_size, void* d_ws, size_t ws_size,
                              hipStream_t stream) {
    const float* x   = (const float*)d_in[0];
    const int*   ei  = (const int*)d_in[1];
    const int*   bat = (const int*)d_in[2];
    const float* W1  = (const float*)d_in[3];
    const float* b1  = (const float*)d_in[4];
    const float* g1  = (const float*)d_in[5];
    const float* be1 = (const float*)d_in[6];
    const float* rm1 = (const float*)d_in[7];
    const float* rv1 = (const float*)d_in[8];
    const float* W2  = (const float*)d_in[9];
    const float* b2  = (const float*)d_in[10];
    const float* g2  = (const float*)d_in[11];
    const float* be2 = (const float*)d_in[12];
    const float* rm2 = (const float*)d_in[13];
    const float* rv2 = (const float*)d_in[14];
    const float* Wh1 = (const float*)d_in[15];
    const float* bh1 = (const float*)d_in[16];
    const float* Wh2 = (const float*)d_in[17];
    const float* bh2 = (const float*)d_in[18];
    const float* Wh3 = (const float*)d_in[19];
    const float* bh3 = (const float*)d_in[20];
    float* out = (float*)d_out;

    char* ws = (char*)d_ws;
    size_t o = 0;
    int*   hblk   = (int*)(ws + o);  o = alignup(o + (size_t)P1_TILES * NBUK * 4);
    int*   rbase  = (int*)(ws + o);  o = alignup(o + (size_t)P1_TILES * NBUK * 4);
    int*   bbase  = (int*)(ws + o);  o = alignup(o + (NBUK + 1) * 4);
    int*   offs   = (int*)(ws + o);  o = alignup(o + (NN + 1) * 4);
    uint32* pairs = (uint32*)(ws + o); o = alignup(o + (size_t)EE * 4);
    int*   col    = (int*)(ws + o);  o = alignup(o + (size_t)EE * 4);
    float* dinv   = (float*)(ws + o); o = alignup(o + (size_t)NN * 4);
    float* scb    = (float*)(ws + o); o = alignup(o + 4 * 64 * 4);
    uint32* Wt1b  = (uint32*)(ws + o); o = alignup(o + 64 * (INF_ / 2) * 4);
    uint32* Wt2b  = (uint32*)(ws + o); o = alignup(o + 64 * (HID / 2) * 4);
    float* msum   = (float*)(ws + o); o += (size_t)GG * 64 * 4;
    float* mmax   = (float*)(ws + o); o += (size_t)GG * 64 * 4;
    float* gcnt   = (float*)(ws + o); o += (size_t)GG * 4;
    o = alignup(o);
    uint32* hwb   = (uint32*)(ws + o); o = alignup(o + ((size_t)NN + 1) * 32 * 4);
    float* h      = (float*)(ws + o); o = alignup(o + (size_t)NN * 64 * 4);
    (void)ws_size; (void)n_in; (void)in_sizes; (void)out_size;

    // CSR hist + setup + pool-zero (one kernel, 3 block roles)
    k_hist1<<<P1_TILES + SETUP_B + ZERO_B, 256, 0, stream>>>(
        ei, hblk, b1, g1, be1, rm1, rv1, b2, g2, be2, rm2, rv2, scb,
        W1, Wt1b, W2, Wt2b, hwb, msum);
    k_scan2<<<1, 512, 0, stream>>>(hblk, bbase, rbase, offs);
    k_p1b<<<P1_TILES, 256, 0, stream>>>(ei, rbase, pairs);
    k_p2<<<NBUK, 256, 0, stream>>>(pairs, bbase, offs, dinv, col);

    // layer 1 (GEMM outputs pre-scaled by dinv)
    k_gemm_mfma<INF_><<<(NN + 63) / 64, 256, 0, stream>>>(x, Wt1b, dinv, hwb, NN);
    k_gcn_gather<<<(NN + 3) / 4, 256, 0, stream>>>(hwb, col, offs, dinv,
                                                   scb, scb + 64, nullptr, h);
    // layer 2 (residual, in-place into h)
    k_gemm_mfma<HID><<<(NN + 63) / 64, 256, 0, stream>>>(h, Wt2b, dinv, hwb, NN);
    k_gcn_gather<<<(NN + 3) / 4, 256, 0, stream>>>(hwb, col, offs, dinv,
                                                   scb + 128, scb + 192, h, h);
    // pooling + head
    k_pool<<<(NN + 127) / 128, 256, 0, stream>>>(h, bat, msum, mmax, gcnt);
    k_head<<<GG, 64, 0, stream>>>(msum, mmax, gcnt, Wh1, bh1, Wh2, bh2, Wh3, bh3, out);
}